// Round 7
// baseline (18769.928 us; speedup 1.0000x reference)
//
#include <hip/hip_runtime.h>
#include <math.h>

#define BTOT 16384
#define MB 16
#define NBLK (BTOT / MB)

// ---- ws float-slot offsets ----
#define WS_WIHT   0        // f32 [64][512]   (k-major, gate-col j)
#define WS_WHHB   32768    // u16 [128][512]  (bf16; 32768 f32 slots)
#define WS_WIH3B  65536    // u16 [64][384]   (bf16 i,g,o; 12288 slots)
#define WS_WQT    77824    // f32 [128][128]
#define WS_WVT    94208    // f32 [j:128][d:128]
#define WS_OUTT   110592   // f32 [128][128]
#define WS_W1T    126976   // f32 [256][128]
#define WS_W2T    159744   // f32 [128][36]
#define PREP_TOTAL 209408  // total prep elements

// ---- LDS pool byte offsets ----
#define L_WHH    0         // u16 128*512 = 131072   (phase A)
#define L_WIH3   0         // u16 64*384 = 49152     (phase B)
#define L_EMBN   49152     // f32 [32][72] = 9216
#define L_HN     58368     // f32 [32][130] = 16640
#define L_QW     75008     // u16 [16][512] = 16384
#define L_Q      91392     // f32 [16][128] = 8192
#define L_NB     99584     // f32 224 -> 896
#define L_SCB    100480    // f32 128
#define L_WB     100992    // f32 128
#define L_RED    101504    // f32 8
#define L_QKB    101536    // f32 64
#define L_CNT    101792    // i32 16  (written in B0, after Whh reads end)
#define L_LOG    101856    // f32 48
#define L_APB    0         // f32 16*128 (post-loop, over Wih3)
#define L_SOCB   8192      // f32 16*128
#define L_HIDB   16384     // f32 16*128
#define L_HW     131072    // u16 [16][512] = 16384  (phase B, over emb)
#define L_EMB    131072    // f32 [64][72] = 18432   (phase A)
#define L_HT     149504    // f32 [16][128] = 8192
#define L_X      157696    // f32 448
#define L_EMBW   159488    // f32 448
#define L_EMBB   161280    // f32 64
#define LDS_BYTES 161536

__device__ __forceinline__ float sigm(float v) { return 1.0f / (1.0f + expf(-v)); }
__device__ __forceinline__ float bf(unsigned short u) { return __uint_as_float(((unsigned int)u) << 16); }
__device__ __forceinline__ unsigned short tob(float f) {
    unsigned int u = __float_as_uint(f);
    return (unsigned short)((u + 0x7fffu + ((u >> 16) & 1u)) >> 16);
}

__global__ void prep_kernel(const float* __restrict__ W_ih, const float* __restrict__ W_hh,
                            const float* __restrict__ in_proj_w, const float* __restrict__ out_proj_w,
                            const float* __restrict__ traj_W1, const float* __restrict__ traj_W2,
                            float* __restrict__ ws) {
    int idx = blockIdx.x * 256 + threadIdx.x;
    if (idx < 32768) { int k = idx >> 9, j = idx & 511; ws[WS_WIHT + idx] = W_ih[j * 64 + k]; return; }
    idx -= 32768;
    if (idx < 65536) { int k = idx >> 9, gc = idx & 511;
        ((unsigned short*)(ws + WS_WHHB))[idx] = tob(W_hh[gc * 128 + k]); return; }
    idx -= 65536;
    if (idx < 24576) { int k = idx / 384, c = idx - k * 384; int gc = (c < 128) ? c : c + 128;
        ((unsigned short*)(ws + WS_WIH3B))[idx] = tob(W_ih[gc * 64 + k]); return; }
    idx -= 24576;
    if (idx < 16384) { int k = idx >> 7, dd = idx & 127; ws[WS_WQT + idx] = in_proj_w[dd * 128 + k]; return; }
    idx -= 16384;
    if (idx < 16384) { int j = idx >> 7, dd = idx & 127; ws[WS_WVT + idx] = in_proj_w[(256 + dd) * 128 + j]; return; }
    idx -= 16384;
    if (idx < 16384) { int k = idx >> 7, dd = idx & 127; ws[WS_OUTT + idx] = out_proj_w[dd * 128 + k]; return; }
    idx -= 16384;
    if (idx < 32768) { int k = idx >> 7, j = idx & 127; ws[WS_W1T + idx] = traj_W1[j * 256 + k]; return; }
    idx -= 32768;
    if (idx < 4608)  { int j = idx / 36, r = idx - j * 36; ws[WS_W2T + idx] = traj_W2[r * 128 + j]; return; }
}

__global__ __launch_bounds__(512, 2)
void traj_kernel(const float* __restrict__ x, const float* __restrict__ neighbors,
                 const int* __restrict__ ncnt,
                 const float* __restrict__ embed_W, const float* __restrict__ embed_b,
                 const float* __restrict__ b_ih, const float* __restrict__ b_hh,
                 const float* __restrict__ in_proj_w, const float* __restrict__ in_proj_b,
                 const float* __restrict__ out_proj_b,
                 const float* __restrict__ traj_b1, const float* __restrict__ traj_b2,
                 const float* __restrict__ prob_W, const float* __restrict__ prob_b,
                 const float* __restrict__ ws, float* __restrict__ out) {
    extern __shared__ char smem[];
    float* sp = (float*)smem;
    unsigned short* spu = (unsigned short*)smem;
    int* cnts = (int*)(smem + L_CNT);

    const int tid = threadIdx.x;
    const int base = blockIdx.x * MB;
    const int d = tid & 127;
    const int mg = tid >> 7;   // 0..3; wave-uniform

    const float* wiht = ws + WS_WIHT;
    const float* wqt  = ws + WS_WQT;
    const float* wvt  = ws + WS_WVT;
    const float* outt = ws + WS_OUTT;
    const float* w1t  = ws + WS_W1T;
    const float* w2t  = ws + WS_W2T;

    // ---- stage small stuff + WhhB copy (NOTE: cnts loaded later, in B0 —
    // L_CNT aliases the WhhB LDS region, which is live through phase A) ----
    if (tid < 448) { sp[L_X/4 + tid] = x[base * 28 + tid]; sp[L_EMBW/4 + tid] = embed_W[tid]; }
    else if (tid < 512) sp[L_EMBB/4 + tid - 448] = embed_b[tid - 448];
    {
        const uint4* src = (const uint4*)(ws + WS_WHHB);
        uint4* dst = (uint4*)(smem + L_WHH);
        #pragma unroll
        for (int r = 0; r < 16; ++r) dst[tid + 512 * r] = src[tid + 512 * r];
    }
    __syncthreads();

    // ---- A1: embed target (64 rows x 64 cols) ----
    #pragma unroll
    for (int r = 0; r < 8; ++r) {
        int idx = r * 512 + tid;
        int e = idx & 63, row = idx >> 6;   // row = m*4+t
        float a = sp[L_EMBB/4 + e];
        #pragma unroll
        for (int f = 0; f < 7; ++f) a = fmaf(sp[L_X/4 + row * 7 + f], sp[L_EMBW/4 + e * 7 + f], a);
        sp[L_EMB/4 + row * 72 + e] = fmaxf(a, 0.0f);
    }
    __syncthreads();

    // ---- A2: ih-preactivations for all 4 steps, all 4 owned elements ----
    float ih[64];  // [i(4)][t(4)][g(4)], static-indexed only
    {
        float bb[4];
        #pragma unroll
        for (int g = 0; g < 4; ++g) bb[g] = b_ih[g * 128 + d] + b_hh[g * 128 + d];
        #pragma unroll
        for (int i = 0; i < 4; ++i)
            #pragma unroll
            for (int t = 0; t < 4; ++t)
                #pragma unroll
                for (int g = 0; g < 4; ++g) ih[i * 16 + t * 4 + g] = bb[g];
    }
    #pragma unroll 2
    for (int k = 0; k < 64; ++k) {
        float w0 = wiht[k * 512 + d], w1 = wiht[k * 512 + 128 + d];
        float w2 = wiht[k * 512 + 256 + d], w3 = wiht[k * 512 + 384 + d];
        #pragma unroll
        for (int i = 0; i < 4; ++i) {
            int m = mg * 4 + i;
            #pragma unroll
            for (int t = 0; t < 4; ++t) {
                float v = sp[L_EMB/4 + (m * 4 + t) * 72 + k];
                ih[i*16 + t*4 + 0] = fmaf(w0, v, ih[i*16 + t*4 + 0]);
                ih[i*16 + t*4 + 1] = fmaf(w1, v, ih[i*16 + t*4 + 1]);
                ih[i*16 + t*4 + 2] = fmaf(w2, v, ih[i*16 + t*4 + 2]);
                ih[i*16 + t*4 + 3] = fmaf(w3, v, ih[i*16 + t*4 + 3]);
            }
        }
    }

    // ---- A3: recurrence. t=0: h=0 so gates = ihpre directly ----
    float c[4];
    #pragma unroll
    for (int i = 0; i < 4; ++i) {
        float ig = sigm(ih[i * 16 + 0]);
        float gg = tanhf(ih[i * 16 + 2]);
        float og = sigm(ih[i * 16 + 3]);
        c[i] = ig * gg;
        sp[L_HT/4 + (mg * 4 + i) * 128 + d] = og * tanhf(c[i]);
    }
    __syncthreads();
    #pragma unroll
    for (int t = 1; t < 4; ++t) {
        float a[4][4];
        #pragma unroll
        for (int i = 0; i < 4; ++i)
            #pragma unroll
            for (int g = 0; g < 4; ++g) a[i][g] = ih[i * 16 + t * 4 + g];
        for (int k = 0; k < 128; k += 4) {
            float4 hv[4];
            #pragma unroll
            for (int i = 0; i < 4; ++i)
                hv[i] = *(const float4*)&sp[L_HT/4 + (mg * 4 + i) * 128 + k];
            #pragma unroll
            for (int kk = 0; kk < 4; ++kk) {
                float w0 = bf(spu[L_WHH/2 + (k + kk) * 512 + d]);
                float w1 = bf(spu[L_WHH/2 + (k + kk) * 512 + 128 + d]);
                float w2 = bf(spu[L_WHH/2 + (k + kk) * 512 + 256 + d]);
                float w3 = bf(spu[L_WHH/2 + (k + kk) * 512 + 384 + d]);
                #pragma unroll
                for (int i = 0; i < 4; ++i) {
                    float v = (kk == 0) ? hv[i].x : (kk == 1) ? hv[i].y : (kk == 2) ? hv[i].z : hv[i].w;
                    a[i][0] = fmaf(w0, v, a[i][0]);
                    a[i][1] = fmaf(w1, v, a[i][1]);
                    a[i][2] = fmaf(w2, v, a[i][2]);
                    a[i][3] = fmaf(w3, v, a[i][3]);
                }
            }
        }
        __syncthreads();
        #pragma unroll
        for (int i = 0; i < 4; ++i) {
            float ig = sigm(a[i][0]);
            float fg = sigm(a[i][1]);
            float gg = tanhf(a[i][2]);
            float og = sigm(a[i][3]);
            c[i] = fg * c[i] + ig * gg;
            sp[L_HT/4 + (mg * 4 + i) * 128 + d] = og * tanhf(c[i]);
        }
        __syncthreads();
    }

    // ---- B0: Wih3 copy (over dead Whh) + cnts load + batched q ----
    {
        const uint4* src = (const uint4*)(ws + WS_WIH3B);
        uint4* dst = (uint4*)(smem + L_WIH3);
        #pragma unroll
        for (int r = 0; r < 6; ++r) dst[tid + 512 * r] = src[tid + 512 * r];
    }
    if (tid < 16) cnts[tid] = ncnt[base + tid];   // safe now: Whh region reads ended
    {
        float qa[4];
        #pragma unroll
        for (int i = 0; i < 4; ++i) qa[i] = in_proj_b[d];
        #pragma unroll 4
        for (int k = 0; k < 128; ++k) {
            float wq = wqt[k * 128 + d];
            #pragma unroll
            for (int i = 0; i < 4; ++i)
                qa[i] = fmaf(wq, sp[L_HT/4 + (mg * 4 + i) * 128 + k], qa[i]);
        }
        __syncthreads();  // Wih3 copy + cnts done; h_t reads done
        #pragma unroll
        for (int i = 0; i < 4; ++i) sp[L_Q/4 + (mg * 4 + i) * 128 + d] = qa[i];
    }
    __syncthreads();

    // ---- Bqw: qW[m][h][j] (bf16) + qkb ----
    {
        const int h = mg, j = d;
        float qw[16];
        #pragma unroll
        for (int m = 0; m < 16; ++m) qw[m] = 0.0f;
        #pragma unroll 2
        for (int dd = 0; dd < 32; ++dd) {
            float wv = in_proj_w[(128 + h * 32 + dd) * 128 + j];
            #pragma unroll
            for (int m = 0; m < 16; ++m)
                qw[m] = fmaf(wv, sp[L_Q/4 + m * 128 + h * 32 + dd], qw[m]);
        }
        #pragma unroll
        for (int m = 0; m < 16; ++m) spu[L_QW/2 + m * 512 + h * 128 + j] = tob(qw[m]);
    }
    if (tid < 64) {
        int m = tid >> 2, h2 = tid & 3;
        float s = 0.0f;
        for (int dd = 0; dd < 32; ++dd)
            s = fmaf(sp[L_Q/4 + m * 128 + h2 * 32 + dd], in_proj_b[128 + h2 * 32 + dd], s);
        sp[L_QKB/4 + tid] = s;
    }

    // ---- neighbor biases ----
    const float bi = b_ih[d] + b_hh[d];
    const float bg = b_ih[256 + d] + b_hh[256 + d];
    const float bo = b_ih[384 + d] + b_hh[384 + d];
    const float scl = 0.17677669529663687f;

    // ---- m-loop ----
    for (int m = 0; m < MB; ++m) {
        __syncthreads();
        if (tid < 224) sp[L_NB/4 + tid] = neighbors[(base + m) * 224 + tid];
        __syncthreads();
        #pragma unroll
        for (int r = 0; r < 4; ++r) {
            int idx = r * 512 + tid;
            int e = idx & 63, n = idx >> 6;
            float a = sp[L_EMBB/4 + e];
            #pragma unroll
            for (int f = 0; f < 7; ++f) a = fmaf(sp[L_NB/4 + n * 7 + f], sp[L_EMBW/4 + e * 7 + f], a);
            sp[L_EMBN/4 + n * 72 + e] = fmaxf(a, 0.0f);
        }
        __syncthreads();
        // neighbor LSTM (i,g,o only; c0=0)
        {
            float aI[8], aG[8], aO[8];
            #pragma unroll
            for (int n = 0; n < 8; ++n) { aI[n] = bi; aG[n] = bg; aO[n] = bo; }
            for (int k = 0; k < 64; k += 4) {
                float4 ev[8];
                #pragma unroll
                for (int n = 0; n < 8; ++n)
                    ev[n] = *(const float4*)&sp[L_EMBN/4 + (mg * 8 + n) * 72 + k];
                #pragma unroll
                for (int kk = 0; kk < 4; ++kk) {
                    float wi = bf(spu[L_WIH3/2 + (k + kk) * 384 + d]);
                    float wg = bf(spu[L_WIH3/2 + (k + kk) * 384 + 128 + d]);
                    float wo = bf(spu[L_WIH3/2 + (k + kk) * 384 + 256 + d]);
                    #pragma unroll
                    for (int n = 0; n < 8; ++n) {
                        float v = (kk == 0) ? ev[n].x : (kk == 1) ? ev[n].y : (kk == 2) ? ev[n].z : ev[n].w;
                        aI[n] = fmaf(wi, v, aI[n]);
                        aG[n] = fmaf(wg, v, aG[n]);
                        aO[n] = fmaf(wo, v, aO[n]);
                    }
                }
            }
            #pragma unroll
            for (int n = 0; n < 8; ++n) {
                float ig = sigm(aI[n]);
                float gg = tanhf(aG[n]);
                float og = sigm(aO[n]);
                sp[L_HN/4 + (mg * 8 + n) * 130 + d] = og * tanhf(ig * gg);
            }
        }
        __syncthreads();
        const int cnt = cnts[m];
        if (tid < 128) {
            int hc = tid >> 5, n = tid & 31;
            float a = 0.0f;
            #pragma unroll 4
            for (int j = 0; j < 128; ++j)
                a = fmaf(bf(spu[L_QW/2 + m * 512 + hc * 128 + j]), sp[L_HN/4 + n * 130 + j], a);
            a = (a + sp[L_QKB/4 + m * 4 + hc]) * scl;
            sp[L_SCB/4 + tid] = (n < cnt) ? a : -1e9f;
        }
        __syncthreads();
        if (tid < 4) {
            float mx = sp[L_SCB/4 + tid * 32];
            for (int n = 1; n < 32; ++n) mx = fmaxf(mx, sp[L_SCB/4 + tid * 32 + n]);
            sp[L_RED/4 + tid] = mx;
        }
        __syncthreads();
        if (tid < 128) sp[L_WB/4 + tid] = expf(sp[L_SCB/4 + tid] - sp[L_RED/4 + (tid >> 5)]);
        __syncthreads();
        if (tid < 4) {
            float s = 0.0f;
            for (int n = 0; n < 32; ++n) s += sp[L_WB/4 + tid * 32 + n];
            sp[L_RED/4 + 4 + tid] = 1.0f / s;
        }
        __syncthreads();
        if (tid < 32) {
            float aw = 0.25f * (sp[L_WB/4 + tid]      * sp[L_RED/4 + 4] +
                                sp[L_WB/4 + 32 + tid] * sp[L_RED/4 + 5] +
                                sp[L_WB/4 + 64 + tid] * sp[L_RED/4 + 6] +
                                sp[L_WB/4 + 96 + tid] * sp[L_RED/4 + 7]);
            out[BTOT * 39 + (base + m) * 32 + tid] = (tid < cnt) ? aw : 0.0f;
        }
        {
            float a = 0.0f;
            #pragma unroll 4
            for (int n = 0; n < 32; ++n)
                a = fmaf(sp[L_WB/4 + mg * 32 + n], sp[L_HN/4 + n * 130 + d], a);
            a *= sp[L_RED/4 + 4 + mg];
            spu[L_HW/2 + m * 512 + mg * 128 + d] = tob(a);
        }
    }
    __syncthreads();

    // ---- Bap: attn pre-projection ----
    {
        const int hcd = d >> 5;
        float ap[4];
        #pragma unroll
        for (int i = 0; i < 4; ++i) ap[i] = in_proj_b[256 + d];
        #pragma unroll 4
        for (int j = 0; j < 128; ++j) {
            float w = wvt[j * 128 + d];
            #pragma unroll
            for (int i = 0; i < 4; ++i)
                ap[i] = fmaf(w, bf(spu[L_HW/2 + (mg * 4 + i) * 512 + hcd * 128 + j]), ap[i]);
        }
        __syncthreads();  // Wih3 region dead; reuse as APB
        #pragma unroll
        for (int i = 0; i < 4; ++i) sp[L_APB/4 + (mg * 4 + i) * 128 + d] = ap[i];
    }
    __syncthreads();
    // ---- Bso: out_proj + has_nb mask ----
    {
        float so[4];
        #pragma unroll
        for (int i = 0; i < 4; ++i) so[i] = out_proj_b[d];
        #pragma unroll 4
        for (int k = 0; k < 128; ++k) {
            float w = outt[k * 128 + d];
            #pragma unroll
            for (int i = 0; i < 4; ++i)
                so[i] = fmaf(w, sp[L_APB/4 + (mg * 4 + i) * 128 + k], so[i]);
        }
        #pragma unroll
        for (int i = 0; i < 4; ++i) {
            int mm = mg * 4 + i;
            sp[L_SOCB/4 + mm * 128 + d] = (cnts[mm] > 0) ? so[i] : 0.0f;
        }
    }
    __syncthreads();
    // ---- Bhid: traj_W1 relu ----
    {
        float hi[4];
        #pragma unroll
        for (int i = 0; i < 4; ++i) hi[i] = traj_b1[d];
        #pragma unroll 4
        for (int k = 0; k < 128; ++k) {
            float w = w1t[k * 128 + d];
            #pragma unroll
            for (int i = 0; i < 4; ++i)
                hi[i] = fmaf(w, sp[L_HT/4 + (mg * 4 + i) * 128 + k], hi[i]);
        }
        #pragma unroll 4
        for (int k = 0; k < 128; ++k) {
            float w = w1t[(128 + k) * 128 + d];
            #pragma unroll
            for (int i = 0; i < 4; ++i)
                hi[i] = fmaf(w, sp[L_SOCB/4 + (mg * 4 + i) * 128 + k], hi[i]);
        }
        #pragma unroll
        for (int i = 0; i < 4; ++i)
            sp[L_HIDB/4 + (mg * 4 + i) * 128 + d] = fmaxf(hi[i], 0.0f);
    }
    if (tid < 48) {
        int mo = tid / 3, r = tid - mo * 3;
        float a = prob_b[r];
        for (int k = 0; k < 128; ++k) a = fmaf(sp[L_HT/4 + mo * 128 + k], prob_W[r * 256 + k], a);
        for (int k = 0; k < 128; ++k) a = fmaf(sp[L_SOCB/4 + mo * 128 + k], prob_W[r * 256 + 128 + k], a);
        sp[L_LOG/4 + tid] = a;
    }
    __syncthreads();
    // ---- Btraj ----
    for (int o = tid; o < 576; o += 512) {
        int mo = o / 36, cc = o - mo * 36;
        float a = traj_b2[cc];
        #pragma unroll 4
        for (int j = 0; j < 128; ++j) a = fmaf(sp[L_HIDB/4 + mo * 128 + j], w2t[j * 36 + cc], a);
        out[(base + mo) * 36 + cc] = a;
    }
    if (tid < 16) {
        float l0 = sp[L_LOG/4 + tid * 3], l1 = sp[L_LOG/4 + tid * 3 + 1], l2 = sp[L_LOG/4 + tid * 3 + 2];
        float mx = fmaxf(l0, fmaxf(l1, l2));
        float e0 = expf(l0 - mx), e1 = expf(l1 - mx), e2 = expf(l2 - mx);
        float inv = 1.0f / (e0 + e1 + e2);
        out[BTOT * 36 + (base + tid) * 3 + 0] = e0 * inv;
        out[BTOT * 36 + (base + tid) * 3 + 1] = e1 * inv;
        out[BTOT * 36 + (base + tid) * 3 + 2] = e2 * inv;
    }
}

extern "C" void kernel_launch(void* const* d_in, const int* in_sizes, int n_in,
                              void* d_out, int out_size, void* d_ws, size_t ws_size,
                              hipStream_t stream) {
    (void)in_sizes; (void)n_in; (void)out_size; (void)ws_size;
    const float* x         = (const float*)d_in[0];
    const float* neighbors = (const float*)d_in[1];
    const int*   ncnt      = (const int*)d_in[2];
    const float* embed_W   = (const float*)d_in[3];
    const float* embed_b   = (const float*)d_in[4];
    const float* W_ih      = (const float*)d_in[5];
    const float* W_hh      = (const float*)d_in[6];
    const float* b_ih      = (const float*)d_in[7];
    const float* b_hh      = (const float*)d_in[8];
    const float* in_proj_w = (const float*)d_in[9];
    const float* in_proj_b = (const float*)d_in[10];
    const float* out_proj_w= (const float*)d_in[11];
    const float* out_proj_b= (const float*)d_in[12];
    const float* traj_W1   = (const float*)d_in[13];
    const float* traj_b1   = (const float*)d_in[14];
    const float* traj_W2   = (const float*)d_in[15];
    const float* traj_b2   = (const float*)d_in[16];
    const float* prob_W    = (const float*)d_in[17];
    const float* prob_b    = (const float*)d_in[18];
    float* ws  = (float*)d_ws;
    float* out = (float*)d_out;

    hipFuncSetAttribute((const void*)traj_kernel,
                        hipFuncAttributeMaxDynamicSharedMemorySize, LDS_BYTES);

    hipLaunchKernelGGL(prep_kernel, dim3(PREP_TOTAL / 256), dim3(256), 0, stream,
                       W_ih, W_hh, in_proj_w, out_proj_w, traj_W1, traj_W2, ws);
    hipLaunchKernelGGL(traj_kernel, dim3(NBLK), dim3(512), LDS_BYTES, stream,
                       x, neighbors, ncnt, embed_W, embed_b, b_ih, b_hh,
                       in_proj_w, in_proj_b, out_proj_b, traj_b1, traj_b2,
                       prob_W, prob_b, ws, out);
}